// Round 1
// baseline (78032.318 us; speedup 1.0000x reference)
//
#include <hip/hip_runtime.h>
#include <math.h>

#define BB   128
#define TT   512
#define INX  3
#define AA   77
#define HH   512
#define KWD  10
#define KMD  20
#define UU   64
#define OUTD 121          // 6*KM+1
#define IN1  80           // INX+AA
#define IN2  592          // INX+AA+HH

#define MT 16             // batch rows per WG
#define NT 16             // hidden units per WG
#define NTILES (HH/NT)    // 32
#define MTILES (BB/MT)    // 8

// LDS pitches (floats): keep float4-aligned (mult of 4) and bank-friendly
#define P_IN1 84
#define P_IN2 596
#define P_H   516

#define BH  (BB*HH)       // 65536
#define BA  (BB*AA)       // 9856
#define BKW (BB*KWD)      // 1280

static_assert(OUTD <= 128, "fc2 thread mapping");

__device__ __forceinline__ float sigf(float x) { return 1.0f / (1.0f + expf(-x)); }

// fc2 + output transforms for one batch row, one timestep. All threads of the
// block must enter (contains barriers). Needs sY[OUTD], sRed[2] shared scratch.
__device__ __forceinline__ void fc2_post(const float* __restrict__ h2r,
                                         const float* __restrict__ W_fc2,
                                         const float* __restrict__ b_fc2,
                                         float* __restrict__ out,
                                         int brow, int tprev, int tid,
                                         float* sY, float* sRed)
{
    if (tid < OUTD) {
        const float4* wr = (const float4*)(W_fc2 + (size_t)tid * HH);
        const float4* hv = (const float4*)h2r;
        float acc = b_fc2[tid];
#pragma unroll 4
        for (int k = 0; k < HH / 4; ++k) {
            float4 h = hv[k], w = wr[k];
            acc += h.x * w.x + h.y * w.y + h.z * w.z + h.w * w.w;
        }
        sY[tid] = acc;
    }
    __syncthreads();
    if (tid == 0) {
        float mx = sY[0];
        for (int i = 1; i < KMD; ++i) mx = fmaxf(mx, sY[i]);
        float s = 0.f;
        for (int i = 0; i < KMD; ++i) s += expf(sY[i] - mx);
        sRed[0] = mx; sRed[1] = s;
    }
    __syncthreads();
    if (tid < OUTD) {
        const size_t SZ = (size_t)BB * TT * KMD;
        const size_t bt = (size_t)brow * TT + tprev;
        float y = sY[tid];
        if      (tid <     KMD) out[             bt * KMD + tid          ] = expf(y - sRed[0]) / sRed[1];
        else if (tid < 2 * KMD) out[    SZ +     bt * KMD + (tid -   KMD)] = y;
        else if (tid < 3 * KMD) out[2 * SZ +     bt * KMD + (tid - 2*KMD)] = y;
        else if (tid < 4 * KMD) out[3 * SZ +     bt * KMD + (tid - 3*KMD)] = expf(y);
        else if (tid < 5 * KMD) out[4 * SZ +     bt * KMD + (tid - 4*KMD)] = expf(y);
        else if (tid < 6 * KMD) out[5 * SZ +     bt * KMD + (tid - 5*KMD)] = tanhf(y);
        else                    out[6 * SZ + bt] = sigf(y);
    }
}

// Step kernel 1: z1 = [x_t, w_pre] @ Wih1^T + h1_old @ Whh1^T + b; LSTM cell -> h1_new, c1.
// Also: fc2+postproc of h2_prev (t-1's output row) on WGs with ntile < MT.
__global__ __launch_bounds__(256) void k1(
    const float* __restrict__ x,
    const float* __restrict__ Wih1, const float* __restrict__ Whh1,
    const float* __restrict__ bih1, const float* __restrict__ bhh1,
    const float* __restrict__ W_fc2, const float* __restrict__ b_fc2,
    const float* __restrict__ h1_old, float* __restrict__ h1_new,
    float* __restrict__ c1,
    const float* __restrict__ w_pre, const float* __restrict__ h2_prev,
    float* __restrict__ out, int t)
{
    __shared__ float sIn[MT][P_IN1];
    __shared__ float sH[MT][P_H];
    __shared__ float sY[OUTD];
    __shared__ float sRed[2];

    const int tid   = threadIdx.x;
    const int ntile = blockIdx.x, mtile = blockIdx.y;
    const int row0  = mtile * MT, unit0 = ntile * NT;

    // stage in1 = [x_t (3), w_pre (77)]
    for (int idx = tid; idx < MT * IN1; idx += 256) {
        int r = idx / IN1, c = idx % IN1;
        int b = row0 + r;
        sIn[r][c] = (c < INX) ? x[((size_t)b * TT + t) * INX + c]
                              : w_pre[(size_t)b * AA + (c - INX)];
    }
    // stage h1_old tile
    for (int idx = tid; idx < MT * HH; idx += 256) {
        int r = idx / HH, c = idx % HH;
        sH[r][c] = h1_old[(size_t)(row0 + r) * HH + c];
    }
    __syncthreads();

    // GEMM + cell: thread owns (m, j), computes 4 gates
    {
        const int m = tid & 15, j = tid >> 4;
        const int uj = unit0 + j;
        float a0 = bih1[uj]          + bhh1[uj];
        float a1 = bih1[HH + uj]     + bhh1[HH + uj];
        float a2 = bih1[2 * HH + uj] + bhh1[2 * HH + uj];
        float a3 = bih1[3 * HH + uj] + bhh1[3 * HH + uj];

        const float4* w0 = (const float4*)(Wih1 + (size_t)uj * IN1);
        const float4* w1 = (const float4*)(Wih1 + (size_t)(HH + uj) * IN1);
        const float4* w2 = (const float4*)(Wih1 + (size_t)(2 * HH + uj) * IN1);
        const float4* w3 = (const float4*)(Wih1 + (size_t)(3 * HH + uj) * IN1);
        const float4* av = (const float4*)(&sIn[m][0]);
#pragma unroll 4
        for (int k = 0; k < IN1 / 4; ++k) {
            float4 a = av[k];
            float4 q0 = w0[k], q1 = w1[k], q2 = w2[k], q3 = w3[k];
            a0 += a.x*q0.x + a.y*q0.y + a.z*q0.z + a.w*q0.w;
            a1 += a.x*q1.x + a.y*q1.y + a.z*q1.z + a.w*q1.w;
            a2 += a.x*q2.x + a.y*q2.y + a.z*q2.z + a.w*q2.w;
            a3 += a.x*q3.x + a.y*q3.y + a.z*q3.z + a.w*q3.w;
        }
        const float4* v0 = (const float4*)(Whh1 + (size_t)uj * HH);
        const float4* v1 = (const float4*)(Whh1 + (size_t)(HH + uj) * HH);
        const float4* v2 = (const float4*)(Whh1 + (size_t)(2 * HH + uj) * HH);
        const float4* v3 = (const float4*)(Whh1 + (size_t)(3 * HH + uj) * HH);
        const float4* hv = (const float4*)(&sH[m][0]);
#pragma unroll 4
        for (int k = 0; k < HH / 4; ++k) {
            float4 a = hv[k];
            float4 q0 = v0[k], q1 = v1[k], q2 = v2[k], q3 = v3[k];
            a0 += a.x*q0.x + a.y*q0.y + a.z*q0.z + a.w*q0.w;
            a1 += a.x*q1.x + a.y*q1.y + a.z*q1.z + a.w*q1.w;
            a2 += a.x*q2.x + a.y*q2.y + a.z*q2.z + a.w*q2.w;
            a3 += a.x*q3.x + a.y*q3.y + a.z*q3.z + a.w*q3.w;
        }
        // gates: i=a0, f=a1, g=a2, o=a3
        const size_t gi = (size_t)(row0 + m) * HH + uj;
        float cold = c1[gi];
        float cn = sigf(a1) * cold + sigf(a0) * tanhf(a2);
        float hn = sigf(a3) * tanhf(cn);
        c1[gi] = cn;
        h1_new[gi] = hn;
    }

    // fc2 of PREVIOUS step's h2 (kernel boundary synced). One WG per batch row.
    if (t > 0 && ntile < MT) {
        const int brow = row0 + ntile;
        fc2_post(h2_prev + (size_t)brow * HH, W_fc2, b_fc2, out, brow, t - 1, tid, sY, sRed);
    }
}

// Step kernel 3: attention (abk, phi, w_t) + z2 GEMM + LSTM2 cell.
__global__ __launch_bounds__(256) void k3(
    const float* __restrict__ x, const float* __restrict__ c_seq,
    const float* __restrict__ Wih2, const float* __restrict__ Whh2,
    const float* __restrict__ bih2, const float* __restrict__ bhh2,
    const float* __restrict__ W_abk, const float* __restrict__ b_abk,
    const float* __restrict__ h1_new, const float* __restrict__ h2_old,
    float* __restrict__ h2_new, float* __restrict__ c2,
    const float* __restrict__ kap_old, float* __restrict__ kap_new,
    float* __restrict__ w_new, int t)
{
    __shared__ float sIn[MT][P_IN2];  // [x(0:3) | w(3:80) | h1(80:592)]
    __shared__ float sH2[MT][P_H];
    __shared__ float sAbk[MT][32];
    __shared__ float sPhi[MT][UU];
    __shared__ float sAl[MT][KWD], sBe[MT][KWD], sKa[MT][KWD];

    const int tid   = threadIdx.x;
    const int ntile = blockIdx.x, mtile = blockIdx.y;
    const int row0  = mtile * MT, unit0 = ntile * NT;

    // stage x and h1_new into sIn; h2_old into sH2
    for (int idx = tid; idx < MT * INX; idx += 256) {
        int r = idx / INX, c = idx % INX;
        sIn[r][c] = x[((size_t)(row0 + r) * TT + t) * INX + c];
    }
    for (int idx = tid; idx < MT * HH; idx += 256) {
        int r = idx / HH, c = idx % HH;
        sIn[r][INX + AA + c] = h1_new[(size_t)(row0 + r) * HH + c];
        sH2[r][c]            = h2_old[(size_t)(row0 + r) * HH + c];
    }
    __syncthreads();

    // ---- attention: 16 groups of 16 threads, one group per batch row ----
    {
        const int g = tid >> 4, l = tid & 15;
        const int brow = row0 + g;
        for (int o = l; o < 3 * KWD; o += 16) {
            const float4* wr = (const float4*)(W_abk + (size_t)o * HH);
            const float4* hv = (const float4*)(&sIn[g][INX + AA]);
            float acc = b_abk[o];
#pragma unroll 4
            for (int k = 0; k < HH / 4; ++k) {
                float4 h = hv[k], w = wr[k];
                acc += h.x*w.x + h.y*w.y + h.z*w.z + h.w*w.w;
            }
            sAbk[g][o] = acc;
        }
        __syncthreads();
        if (l < KWD) {
            float al = expf(sAbk[g][l]);
            float be = expf(sAbk[g][KWD + l]);
            float ka = kap_old[(size_t)brow * KWD + l] + expf(sAbk[g][2 * KWD + l]);
            sAl[g][l] = al; sBe[g][l] = be; sKa[g][l] = ka;
            kap_new[(size_t)brow * KWD + l] = ka;  // duplicate identical writes: benign
        }
        __syncthreads();
        for (int u = l; u < UU; u += 16) {
            float s = 0.f;
#pragma unroll
            for (int k = 0; k < KWD; ++k) {
                float d = sKa[g][k] - (float)u;
                s += sAl[g][k] * expf(-sBe[g][k] * d * d);
            }
            sPhi[g][u] = s;
        }
        __syncthreads();
        for (int a = l; a < AA; a += 16) {
            float s = 0.f;
            const float* cp = c_seq + (size_t)brow * UU * AA + a;
#pragma unroll 4
            for (int u = 0; u < UU; ++u) s += sPhi[g][u] * cp[(size_t)u * AA];
            sIn[g][INX + a] = s;
            w_new[(size_t)brow * AA + a] = s;  // duplicate identical writes: benign
        }
    }
    __syncthreads();

    // ---- z2 GEMM + cell ----
    {
        const int m = tid & 15, j = tid >> 4;
        const int uj = unit0 + j;
        float a0 = bih2[uj]          + bhh2[uj];
        float a1 = bih2[HH + uj]     + bhh2[HH + uj];
        float a2 = bih2[2 * HH + uj] + bhh2[2 * HH + uj];
        float a3 = bih2[3 * HH + uj] + bhh2[3 * HH + uj];

        const float4* w0 = (const float4*)(Wih2 + (size_t)uj * IN2);
        const float4* w1 = (const float4*)(Wih2 + (size_t)(HH + uj) * IN2);
        const float4* w2 = (const float4*)(Wih2 + (size_t)(2 * HH + uj) * IN2);
        const float4* w3 = (const float4*)(Wih2 + (size_t)(3 * HH + uj) * IN2);
        const float4* av = (const float4*)(&sIn[m][0]);
#pragma unroll 4
        for (int k = 0; k < IN2 / 4; ++k) {
            float4 a = av[k];
            float4 q0 = w0[k], q1 = w1[k], q2 = w2[k], q3 = w3[k];
            a0 += a.x*q0.x + a.y*q0.y + a.z*q0.z + a.w*q0.w;
            a1 += a.x*q1.x + a.y*q1.y + a.z*q1.z + a.w*q1.w;
            a2 += a.x*q2.x + a.y*q2.y + a.z*q2.z + a.w*q2.w;
            a3 += a.x*q3.x + a.y*q3.y + a.z*q3.z + a.w*q3.w;
        }
        const float4* v0 = (const float4*)(Whh2 + (size_t)uj * HH);
        const float4* v1 = (const float4*)(Whh2 + (size_t)(HH + uj) * HH);
        const float4* v2 = (const float4*)(Whh2 + (size_t)(2 * HH + uj) * HH);
        const float4* v3 = (const float4*)(Whh2 + (size_t)(3 * HH + uj) * HH);
        const float4* hv = (const float4*)(&sH2[m][0]);
#pragma unroll 4
        for (int k = 0; k < HH / 4; ++k) {
            float4 a = hv[k];
            float4 q0 = v0[k], q1 = v1[k], q2 = v2[k], q3 = v3[k];
            a0 += a.x*q0.x + a.y*q0.y + a.z*q0.z + a.w*q0.w;
            a1 += a.x*q1.x + a.y*q1.y + a.z*q1.z + a.w*q1.w;
            a2 += a.x*q2.x + a.y*q2.y + a.z*q2.z + a.w*q2.w;
            a3 += a.x*q3.x + a.y*q3.y + a.z*q3.z + a.w*q3.w;
        }
        const size_t gi = (size_t)(row0 + m) * HH + uj;
        float cold = c2[gi];
        float cn = sigf(a1) * cold + sigf(a0) * tanhf(a2);
        float hn = sigf(a3) * tanhf(cn);
        c2[gi] = cn;
        h2_new[gi] = hn;
    }
}

// Final fc2 for t = T-1 (h2 of the last step).
__global__ __launch_bounds__(128) void fc2_final(
    const float* __restrict__ h2_last,
    const float* __restrict__ W_fc2, const float* __restrict__ b_fc2,
    float* __restrict__ out)
{
    __shared__ float sY[OUTD];
    __shared__ float sRed[2];
    const int brow = blockIdx.x;
    fc2_post(h2_last + (size_t)brow * HH, W_fc2, b_fc2, out, brow, TT - 1, threadIdx.x, sY, sRed);
}

extern "C" void kernel_launch(void* const* d_in, const int* in_sizes, int n_in,
                              void* d_out, int out_size, void* d_ws, size_t ws_size,
                              hipStream_t stream) {
    const float* x     = (const float*)d_in[0];
    const float* c_seq = (const float*)d_in[1];
    const float* Wih1  = (const float*)d_in[2];
    const float* Whh1  = (const float*)d_in[3];
    const float* bih1  = (const float*)d_in[4];
    const float* bhh1  = (const float*)d_in[5];
    const float* Wih2  = (const float*)d_in[6];
    const float* Whh2  = (const float*)d_in[7];
    const float* bih2  = (const float*)d_in[8];
    const float* bhh2  = (const float*)d_in[9];
    const float* W_abk = (const float*)d_in[10];
    const float* b_abk = (const float*)d_in[11];
    const float* W_fc2 = (const float*)d_in[12];
    const float* b_fc2 = (const float*)d_in[13];
    float* out = (float*)d_out;

    float* ws  = (float*)d_ws;
    float* h1b = ws;                 // 2*BH (double buffer)
    float* h2b = ws + 2 * BH;        // 2*BH
    float* c1  = ws + 4 * BH;        // BH
    float* c2  = ws + 5 * BH;        // BH
    float* kap = ws + 6 * BH;        // 2*BKW
    float* wb  = ws + 6 * BH + 2 * BKW;  // 2*BA
    const size_t used = (size_t)6 * BH + 2 * BKW + 2 * BA;

    // zero-init recurrent state (ws is poisoned 0xAA before every timed launch)
    hipMemsetAsync(d_ws, 0, used * sizeof(float), stream);

    dim3 grid(NTILES, MTILES), blk(256);
    for (int t = 0; t < TT; ++t) {
        int p = t & 1;
        k1<<<grid, blk, 0, stream>>>(x, Wih1, Whh1, bih1, bhh1, W_fc2, b_fc2,
                                     h1b + (size_t)p * BH, h1b + (size_t)(1 - p) * BH, c1,
                                     wb + (size_t)p * BA, h2b + (size_t)p * BH, out, t);
        k3<<<grid, blk, 0, stream>>>(x, c_seq, Wih2, Whh2, bih2, bhh2, W_abk, b_abk,
                                     h1b + (size_t)(1 - p) * BH,
                                     h2b + (size_t)p * BH, h2b + (size_t)(1 - p) * BH, c2,
                                     kap + (size_t)p * BKW, kap + (size_t)(1 - p) * BKW,
                                     wb + (size_t)(1 - p) * BA, t);
    }
    // last step's output row (T is even -> final h2 is in buffer 0)
    fc2_final<<<dim3(BB), dim3(128), 0, stream>>>(h2b + (size_t)(TT & 1) * BH, W_fc2, b_fc2, out);
}

// Round 3
// 48081.287 us; speedup vs baseline: 1.6229x; 1.6229x over previous
//
#include <hip/hip_runtime.h>
#include <math.h>

#define BB   128
#define TT   512
#define INX  3
#define AA   77
#define HH   512
#define KWD  10
#define KMD  20
#define UU   64
#define OUTD 121          // 6*KM+1
#define IN1  80           // INX+AA
#define IN2  592          // INX+AA+HH

#define MT   8            // batch rows per WG
#define NU   8            // units per WG (gate-rows per WG = 4*NU = 32)
#define GRT  (HH/NU)      // 64 gate-row tiles
#define MTL  (BB/MT)      // 16 batch tiles

// LDS pitches (floats): float4-aligned rows; (pitch mod 32) spreads banks
#define P1   84
#define P2   596
#define PH   516
#define PZ   36

#define BH   (BB*HH)      // 65536
#define BA   (BB*AA)      // 9856
#define BKW  (BB*KWD)     // 1280

__device__ __forceinline__ float sigf(float x) { return 1.0f / (1.0f + expf(-x)); }

__device__ __forceinline__ float dot4(float4 w, float4 a) {
    return w.x * a.x + w.y * a.y + w.z * a.z + w.w * a.w;
}

// fc2 + output transforms for one batch row, one timestep. All threads of the
// block must enter (contains barriers). tid<121 active.
__device__ __forceinline__ void fc2_post(const float* __restrict__ h2r,
                                         const float* __restrict__ W_fc2,
                                         const float* __restrict__ b_fc2,
                                         float* __restrict__ out,
                                         int brow, int tprev, int tid,
                                         float* sY, float* sRed)
{
    if (tid < OUTD) {
        const float4* wr = (const float4*)(W_fc2 + (size_t)tid * HH);
        const float4* hv = (const float4*)h2r;
        float acc = b_fc2[tid];
#pragma unroll 4
        for (int k = 0; k < HH / 4; ++k)
            acc += dot4(wr[k], hv[k]);
        sY[tid] = acc;
    }
    __syncthreads();
    if (tid == 0) {
        float mx = sY[0];
        for (int i = 1; i < KMD; ++i) mx = fmaxf(mx, sY[i]);
        float s = 0.f;
        for (int i = 0; i < KMD; ++i) s += expf(sY[i] - mx);
        sRed[0] = mx; sRed[1] = s;
    }
    __syncthreads();
    if (tid < OUTD) {
        const size_t SZ = (size_t)BB * TT * KMD;
        const size_t bt = (size_t)brow * TT + tprev;
        float y = sY[tid];
        if      (tid <     KMD) out[             bt * KMD + tid          ] = expf(y - sRed[0]) / sRed[1];
        else if (tid < 2 * KMD) out[    SZ +     bt * KMD + (tid -   KMD)] = y;
        else if (tid < 3 * KMD) out[2 * SZ +     bt * KMD + (tid - 2*KMD)] = y;
        else if (tid < 4 * KMD) out[3 * SZ +     bt * KMD + (tid - 3*KMD)] = expf(y);
        else if (tid < 5 * KMD) out[4 * SZ +     bt * KMD + (tid - 4*KMD)] = expf(y);
        else if (tid < 6 * KMD) out[5 * SZ +     bt * KMD + (tid - 5*KMD)] = tanhf(y);
        else                    out[6 * SZ + bt] = sigf(y);
    }
}

// k1: z1 = [x_t, w_pre] @ Wih1^T + h1_old @ Whh1^T + b; cell -> h1_new, c1.
// Also fc2+postproc of h2_prev on WGs with grt < MT (one WG per batch row).
__global__ __launch_bounds__(256, 4) void k1(
    const float* __restrict__ x,
    const float* __restrict__ Wih1, const float* __restrict__ Whh1,
    const float* __restrict__ bih1, const float* __restrict__ bhh1,
    const float* __restrict__ W_fc2, const float* __restrict__ b_fc2,
    const float* __restrict__ h1_old, float* __restrict__ h1_new,
    float* __restrict__ c1,
    const float* __restrict__ w_pre, const float* __restrict__ h2_prev,
    float* __restrict__ out, int t)
{
    __shared__ float sIn[MT][P1];
    __shared__ float sH[MT][PH];
    __shared__ float sZ[MT][PZ];
    __shared__ float sY[OUTD];
    __shared__ float sRed[2];

    const int tid  = threadIdx.x;
    const int grt  = blockIdx.x;     // 0..63
    const int mtl  = blockIdx.y;     // 0..15
    const int row0 = mtl * MT, unit0 = grt * NU;

    // ---- stage activations ----
    {
        const int r = tid >> 5, c0 = tid & 31;
        const int b = row0 + r;
        for (int c = c0; c < IN1; c += 32)
            sIn[r][c] = (c < INX) ? x[((size_t)b * TT + t) * INX + c]
                                  : w_pre[(size_t)b * AA + (c - INX)];
        const float4* src = (const float4*)(h1_old + (size_t)b * HH);
        float4* dst = (float4*)&sH[r][0];
        for (int c = c0; c < HH / 4; c += 32) dst[c] = src[c];
    }
    __syncthreads();

    // ---- GEMM: thread = (m = tid&7, s = tid>>3); s = gate*8 + unit-local ----
    {
        const int m = tid & 7, s = tid >> 3;
        const int g = s >> 3, jl = s & 7;
        const int wrow = g * HH + unit0 + jl;
        float acc0 = bih1[wrow] + bhh1[wrow], acc1 = 0.f, acc2 = 0.f, acc3 = 0.f;

        const float4* wp = (const float4*)(Wih1 + (size_t)wrow * IN1);
        const float4* ap = (const float4*)&sIn[m][0];
#pragma unroll
        for (int k = 0; k < IN1 / 4; k += 4) {
            float4 w0 = wp[k], w1 = wp[k+1], w2 = wp[k+2], w3 = wp[k+3];
            float4 a0 = ap[k], a1 = ap[k+1], a2 = ap[k+2], a3 = ap[k+3];
            acc0 += dot4(w0, a0); acc1 += dot4(w1, a1);
            acc2 += dot4(w2, a2); acc3 += dot4(w3, a3);
        }
        const float4* vp = (const float4*)(Whh1 + (size_t)wrow * HH);
        const float4* hp = (const float4*)&sH[m][0];
#pragma unroll 2
        for (int k = 0; k < HH / 4; k += 4) {
            float4 w0 = vp[k], w1 = vp[k+1], w2 = vp[k+2], w3 = vp[k+3];
            float4 a0 = hp[k], a1 = hp[k+1], a2 = hp[k+2], a3 = hp[k+3];
            acc0 += dot4(w0, a0); acc1 += dot4(w1, a1);
            acc2 += dot4(w2, a2); acc3 += dot4(w3, a3);
        }
        sZ[m][s] = acc0 + acc1 + acc2 + acc3;
    }
    __syncthreads();

    // ---- cell: 64 threads, one (m, unit) each ----
    if (tid < MT * NU) {
        const int m = tid & 7, jl = tid >> 3;
        const float zi = sZ[m][jl],      zf = sZ[m][8 + jl];
        const float zg = sZ[m][16 + jl], zo = sZ[m][24 + jl];
        const size_t gi = (size_t)(row0 + m) * HH + unit0 + jl;
        const float cold = c1[gi];
        const float cn = sigf(zf) * cold + sigf(zi) * tanhf(zg);
        c1[gi] = cn;
        h1_new[gi] = sigf(zo) * tanhf(cn);
    }

    // ---- fc2 of previous step's h2 (rows = mtl*8 + grt for grt<8) ----
    if (t > 0 && grt < MT) {
        const int brow = row0 + grt;
        fc2_post(h2_prev + (size_t)brow * HH, W_fc2, b_fc2, out, brow, t - 1, tid, sY, sRed);
    }
}

// k2: attention for one batch row per WG: abk matvec, alpha/beta/kappa, phi, w_t.
__global__ __launch_bounds__(256) void k2(
    const float* __restrict__ c_seq,
    const float* __restrict__ W_abk, const float* __restrict__ b_abk,
    const float* __restrict__ h1_cur,
    const float* __restrict__ kap_old, float* __restrict__ kap_new,
    float* __restrict__ w_new)
{
    __shared__ float sH1[HH];
    __shared__ float sAbk[32];
    __shared__ float sAl[KWD], sBe[KWD], sKa[KWD];
    __shared__ float sPhi[UU];

    const int tid = threadIdx.x;
    const int b   = blockIdx.x;

    if (tid < HH / 4)
        ((float4*)sH1)[tid] = ((const float4*)(h1_cur + (size_t)b * HH))[tid];
    __syncthreads();

    // abk: 30 rows x K=512, 8-way K-split per row
    {
        const int o = tid >> 3, kk = tid & 7;
        float acc = 0.f;
        if (o < 3 * KWD) {
            const float4* wp = (const float4*)(W_abk + (size_t)o * HH) + kk * 16;
            const float4* hp = (const float4*)sH1 + kk * 16;
#pragma unroll
            for (int k = 0; k < 16; ++k)
                acc += dot4(wp[k], hp[k]);
        }
        acc += __shfl_xor(acc, 1);
        acc += __shfl_xor(acc, 2);
        acc += __shfl_xor(acc, 4);
        if (o < 3 * KWD && kk == 0) sAbk[o] = acc + b_abk[o];
    }
    __syncthreads();

    if (tid < KWD) {
        const float al = expf(sAbk[tid]);
        const float be = expf(sAbk[KWD + tid]);
        const float ka = kap_old[(size_t)b * KWD + tid] + expf(sAbk[2 * KWD + tid]);
        sAl[tid] = al; sBe[tid] = be; sKa[tid] = ka;
        kap_new[(size_t)b * KWD + tid] = ka;
    }
    __syncthreads();

    if (tid < UU) {
        const float u = (float)tid;
        float s = 0.f;
#pragma unroll
        for (int k = 0; k < KWD; ++k) {
            const float d = sKa[k] - u;
            s += sAl[k] * expf(-sBe[k] * d * d);
        }
        sPhi[tid] = s;
    }
    __syncthreads();

    if (tid < AA) {
        float s = 0.f;
        const float* cp = c_seq + (size_t)b * UU * AA + tid;
#pragma unroll 4
        for (int u = 0; u < UU; ++u) s += sPhi[u] * cp[(size_t)u * AA];
        w_new[(size_t)b * AA + tid] = s;
    }
}

// k3: z2 = [x_t, w_t, h1] @ Wih2^T + h2_old @ Whh2^T + b; cell -> h2_new, c2.
__global__ __launch_bounds__(256, 4) void k3(
    const float* __restrict__ x,
    const float* __restrict__ Wih2, const float* __restrict__ Whh2,
    const float* __restrict__ bih2, const float* __restrict__ bhh2,
    const float* __restrict__ h1_cur, const float* __restrict__ w_cur,
    const float* __restrict__ h2_old, float* __restrict__ h2_new,
    float* __restrict__ c2, int t)
{
    __shared__ float sIn[MT][P2];   // [x(3) | w(77) | h1(512)]
    __shared__ float sH2[MT][PH];
    __shared__ float sZ[MT][PZ];

    const int tid  = threadIdx.x;
    const int grt  = blockIdx.x;
    const int mtl  = blockIdx.y;
    const int row0 = mtl * MT, unit0 = grt * NU;

    // ---- stage activations ----
    {
        const int r = tid >> 5, c0 = tid & 31;
        const int b = row0 + r;
        for (int c = c0; c < IN1; c += 32)
            sIn[r][c] = (c < INX) ? x[((size_t)b * TT + t) * INX + c]
                                  : w_cur[(size_t)b * AA + (c - INX)];
        const float4* s1 = (const float4*)(h1_cur + (size_t)b * HH);
        float4* d1 = (float4*)&sIn[r][IN1];
        const float4* s2 = (const float4*)(h2_old + (size_t)b * HH);
        float4* d2 = (float4*)&sH2[r][0];
        for (int c = c0; c < HH / 4; c += 32) { d1[c] = s1[c]; d2[c] = s2[c]; }
    }
    __syncthreads();

    // ---- GEMM ----
    {
        const int m = tid & 7, s = tid >> 3;
        const int g = s >> 3, jl = s & 7;
        const int wrow = g * HH + unit0 + jl;
        float acc0 = bih2[wrow] + bhh2[wrow], acc1 = 0.f, acc2 = 0.f, acc3 = 0.f;

        const float4* wp = (const float4*)(Wih2 + (size_t)wrow * IN2);
        const float4* ap = (const float4*)&sIn[m][0];
#pragma unroll 2
        for (int k = 0; k < IN2 / 4; k += 4) {
            float4 w0 = wp[k], w1 = wp[k+1], w2 = wp[k+2], w3 = wp[k+3];
            float4 a0 = ap[k], a1 = ap[k+1], a2 = ap[k+2], a3 = ap[k+3];
            acc0 += dot4(w0, a0); acc1 += dot4(w1, a1);
            acc2 += dot4(w2, a2); acc3 += dot4(w3, a3);
        }
        const float4* vp = (const float4*)(Whh2 + (size_t)wrow * HH);
        const float4* hp = (const float4*)&sH2[m][0];
#pragma unroll 2
        for (int k = 0; k < HH / 4; k += 4) {
            float4 w0 = vp[k], w1 = vp[k+1], w2 = vp[k+2], w3 = vp[k+3];
            float4 a0 = hp[k], a1 = hp[k+1], a2 = hp[k+2], a3 = hp[k+3];
            acc0 += dot4(w0, a0); acc1 += dot4(w1, a1);
            acc2 += dot4(w2, a2); acc3 += dot4(w3, a3);
        }
        sZ[m][s] = acc0 + acc1 + acc2 + acc3;
    }
    __syncthreads();

    // ---- cell ----
    if (tid < MT * NU) {
        const int m = tid & 7, jl = tid >> 3;
        const float zi = sZ[m][jl],      zf = sZ[m][8 + jl];
        const float zg = sZ[m][16 + jl], zo = sZ[m][24 + jl];
        const size_t gi = (size_t)(row0 + m) * HH + unit0 + jl;
        const float cold = c2[gi];
        const float cn = sigf(zf) * cold + sigf(zi) * tanhf(zg);
        c2[gi] = cn;
        h2_new[gi] = sigf(zo) * tanhf(cn);
    }
}

// Final fc2 for t = T-1.
__global__ __launch_bounds__(128) void fc2_final(
    const float* __restrict__ h2_last,
    const float* __restrict__ W_fc2, const float* __restrict__ b_fc2,
    float* __restrict__ out)
{
    __shared__ float sY[OUTD];
    __shared__ float sRed[2];
    const int brow = blockIdx.x;
    fc2_post(h2_last + (size_t)brow * HH, W_fc2, b_fc2, out, brow, TT - 1, threadIdx.x, sY, sRed);
}

extern "C" void kernel_launch(void* const* d_in, const int* in_sizes, int n_in,
                              void* d_out, int out_size, void* d_ws, size_t ws_size,
                              hipStream_t stream) {
    const float* x     = (const float*)d_in[0];
    const float* c_seq = (const float*)d_in[1];
    const float* Wih1  = (const float*)d_in[2];
    const float* Whh1  = (const float*)d_in[3];
    const float* bih1  = (const float*)d_in[4];
    const float* bhh1  = (const float*)d_in[5];
    const float* Wih2  = (const float*)d_in[6];
    const float* Whh2  = (const float*)d_in[7];
    const float* bih2  = (const float*)d_in[8];
    const float* bhh2  = (const float*)d_in[9];
    const float* W_abk = (const float*)d_in[10];
    const float* b_abk = (const float*)d_in[11];
    const float* W_fc2 = (const float*)d_in[12];
    const float* b_fc2 = (const float*)d_in[13];
    float* out = (float*)d_out;

    float* ws  = (float*)d_ws;
    float* h1b = ws;                     // 2*BH (double buffer)
    float* h2b = ws + 2 * BH;            // 2*BH
    float* c1  = ws + 4 * BH;            // BH
    float* c2  = ws + 5 * BH;            // BH
    float* kap = ws + 6 * BH;            // 2*BKW
    float* wb  = ws + 6 * BH + 2 * BKW;  // 2*BA
    const size_t used = (size_t)6 * BH + 2 * BKW + 2 * BA;

    hipMemsetAsync(d_ws, 0, used * sizeof(float), stream);

    const dim3 grid(GRT, MTL), blk(256);
    for (int t = 0; t < TT; ++t) {
        const int p = t & 1;
        k1<<<grid, blk, 0, stream>>>(x, Wih1, Whh1, bih1, bhh1, W_fc2, b_fc2,
                                     h1b + (size_t)p * BH, h1b + (size_t)(1 - p) * BH, c1,
                                     wb + (size_t)p * BA, h2b + (size_t)p * BH, out, t);
        k2<<<dim3(BB), blk, 0, stream>>>(c_seq, W_abk, b_abk,
                                         h1b + (size_t)(1 - p) * BH,
                                         kap + (size_t)p * BKW, kap + (size_t)(1 - p) * BKW,
                                         wb + (size_t)(1 - p) * BA);
        k3<<<grid, blk, 0, stream>>>(x, Wih2, Whh2, bih2, bhh2,
                                     h1b + (size_t)(1 - p) * BH, wb + (size_t)(1 - p) * BA,
                                     h2b + (size_t)p * BH, h2b + (size_t)(1 - p) * BH, c2, t);
    }
    fc2_final<<<dim3(BB), dim3(128), 0, stream>>>(h2b, W_fc2, b_fc2, out);
}

// Round 5
// 43824.051 us; speedup vs baseline: 1.7806x; 1.0971x over previous
//
#include <hip/hip_runtime.h>
#include <math.h>

#define BB   128
#define TT   512
#define INX  3
#define AA   77
#define HH   512
#define KWD  10
#define KMD  20
#define UU   64
#define OUTD 121          // 6*KM+1
#define IN1  80           // INX+AA
#define IN2  592          // INX+AA+HH

// k1/k3 thread layout: 512 threads = m(8) x j(16) x kq(4)
#define MT   8            // batch rows per WG
#define NJ   16           // units per WG
#define GRT  (HH/NJ)      // 32 unit tiles
#define MTL  (BB/MT)      // 16 batch tiles

// LDS pitches in floats; (pitch % 32) == 20 -> 8 m-rows hit disjoint bank quads
#define PC1  596          // k1 concat row: 148 f4 (+1 f4 pad)
#define PC3  1108         // k3 concat row: 276 f4 (+1 f4 pad)

#define BH   (BB*HH)      // 65536
#define BA   (BB*AA)      // 9856
#define BKW  (BB*KWD)     // 1280

__device__ __forceinline__ float sigf(float x) { return 1.0f / (1.0f + expf(-x)); }

__device__ __forceinline__ float dot4(float4 w, float4 a) {
    return w.x * a.x + w.y * a.y + w.z * a.z + w.w * a.w;
}

// fc2 + output transforms for one batch row, one timestep. Block-uniform entry
// (contains barriers); tid<121 active.
__device__ __forceinline__ void fc2_post(const float* __restrict__ h2r,
                                         const float* __restrict__ W_fc2,
                                         const float* __restrict__ b_fc2,
                                         float* __restrict__ out,
                                         int brow, int tprev, int tid,
                                         float* sY, float* sRed)
{
    if (tid < OUTD) {
        const float4* wr = (const float4*)(W_fc2 + (size_t)tid * HH);
        const float4* hv = (const float4*)h2r;
        float acc = b_fc2[tid];
#pragma unroll 4
        for (int k = 0; k < HH / 4; ++k)
            acc += dot4(wr[k], hv[k]);
        sY[tid] = acc;
    }
    __syncthreads();
    if (tid == 0) {
        float mx = sY[0];
        for (int i = 1; i < KMD; ++i) mx = fmaxf(mx, sY[i]);
        float s = 0.f;
        for (int i = 0; i < KMD; ++i) s += expf(sY[i] - mx);
        sRed[0] = mx; sRed[1] = s;
    }
    __syncthreads();
    if (tid < OUTD) {
        const size_t SZ = (size_t)BB * TT * KMD;
        const size_t bt = (size_t)brow * TT + tprev;
        float y = sY[tid];
        if      (tid <     KMD) out[             bt * KMD + tid          ] = expf(y - sRed[0]) / sRed[1];
        else if (tid < 2 * KMD) out[    SZ +     bt * KMD + (tid -   KMD)] = y;
        else if (tid < 3 * KMD) out[2 * SZ +     bt * KMD + (tid - 2*KMD)] = y;
        else if (tid < 4 * KMD) out[3 * SZ +     bt * KMD + (tid - 3*KMD)] = expf(y);
        else if (tid < 5 * KMD) out[4 * SZ +     bt * KMD + (tid - 4*KMD)] = expf(y);
        else if (tid < 6 * KMD) out[5 * SZ +     bt * KMD + (tid - 5*KMD)] = tanhf(y);
        else                    out[6 * SZ + bt] = sigf(y);
    }
}

// k1: z1 = Wih1@[x,w_pre] + Whh1@h1_old + b; cell -> h1_new, c1.
// Thread (m,j,kq) computes 4 gate partial dots over K-quarter; partials in LDS.
// WGs with grt<8 also run fc2 of h2_prev (one batch row each).
__global__ __launch_bounds__(512, 4) void k1(
    const float* __restrict__ x,
    const float* __restrict__ Wih1, const float* __restrict__ Whh1,
    const float* __restrict__ bih1, const float* __restrict__ bhh1,
    const float* __restrict__ W_fc2, const float* __restrict__ b_fc2,
    const float* __restrict__ h1_old, float* __restrict__ h1_new,
    float* __restrict__ c1,
    const float* __restrict__ w_pre, const float* __restrict__ h2_prev,
    float* __restrict__ out, int t)
{
    __shared__ float sCat[MT][PC1];      // [x(3)|w_pre(77)|h1(512)] = 148 f4
    __shared__ float sZp[4][MT][68];     // kq, m, slot g*16+j (padded)
    __shared__ float sY[OUTD];
    __shared__ float sRed[2];

    const int tid  = threadIdx.x;
    const int grt  = blockIdx.x;         // 0..31
    const int mtl  = blockIdx.y;         // 0..15
    const int row0 = mtl * MT, unit0 = grt * NJ;

    // ---- stage: 8 rows x 148 f4, 64 lanes per row ----
    {
        const int r = tid >> 6, c = tid & 63;
        const int b = row0 + r;
        const float4* s1 = (const float4*)(h1_old + (size_t)b * HH);
        float4* d1 = (float4*)&sCat[r][IN1];
        for (int i = c; i < HH / 4; i += 64) d1[i] = s1[i];
        for (int i = c; i < IN1; i += 64)
            sCat[r][i] = (i < INX) ? x[((size_t)b * TT + t) * INX + i]
                                   : w_pre[(size_t)b * AA + (i - INX)];
    }
    __syncthreads();

    // ---- GEMM: 4 gates per thread over K-quarter ----
    {
        const int m = tid & 7, j = (tid >> 3) & 15, kq = tid >> 7;
        const int i0 = kq * 37, i1 = i0 + 37;      // f4 indices into 148
        const int u = unit0 + j;
        float a0 = 0.f, a1 = 0.f, a2 = 0.f, a3 = 0.f;
        const float4* sc = (const float4*)&sCat[m][0];

        const float4* w0a = (const float4*)Wih1 + (size_t)u * 20;
        const float4* w1a = (const float4*)Wih1 + (size_t)(HH + u) * 20;
        const float4* w2a = (const float4*)Wih1 + (size_t)(2 * HH + u) * 20;
        const float4* w3a = (const float4*)Wih1 + (size_t)(3 * HH + u) * 20;
        const int aEnd = (i1 < 20) ? i1 : 20;
        for (int i = i0; i < aEnd; ++i) {           // only kq==0 enters
            float4 a = sc[i];
            a0 += dot4(w0a[i], a); a1 += dot4(w1a[i], a);
            a2 += dot4(w2a[i], a); a3 += dot4(w3a[i], a);
        }
        const float4* w0b = (const float4*)Whh1 + (size_t)u * 128;
        const float4* w1b = (const float4*)Whh1 + (size_t)(HH + u) * 128;
        const float4* w2b = (const float4*)Whh1 + (size_t)(2 * HH + u) * 128;
        const float4* w3b = (const float4*)Whh1 + (size_t)(3 * HH + u) * 128;
        const int bSt = (i0 > 20) ? i0 : 20;
#pragma unroll 4
        for (int i = bSt; i < i1; ++i) {
            float4 a = sc[i];
            const int k = i - 20;
            a0 += dot4(w0b[k], a); a1 += dot4(w1b[k], a);
            a2 += dot4(w2b[k], a); a3 += dot4(w3b[k], a);
        }
        sZp[kq][m][j]      = a0;
        sZp[kq][m][16 + j] = a1;
        sZp[kq][m][32 + j] = a2;
        sZp[kq][m][48 + j] = a3;
    }
    __syncthreads();

    // ---- cell: 128 threads, thread = (m = tid>>4, j = tid&15) ----
    if (tid < MT * NJ) {
        const int m = tid >> 4, j = tid & 15;
        const int u = unit0 + j;
        float z[4];
#pragma unroll
        for (int g = 0; g < 4; ++g) {
            const int wr = g * HH + u;
            z[g] = bih1[wr] + bhh1[wr]
                 + sZp[0][m][g * 16 + j] + sZp[1][m][g * 16 + j]
                 + sZp[2][m][g * 16 + j] + sZp[3][m][g * 16 + j];
        }
        const size_t gi = (size_t)(row0 + m) * HH + u;
        const float cold = c1[gi];
        const float cn = sigf(z[1]) * cold + sigf(z[0]) * tanhf(z[2]);
        c1[gi] = cn;
        h1_new[gi] = sigf(z[3]) * tanhf(cn);
    }

    // ---- fc2 of previous step's h2 ----
    if (t > 0 && grt < MT) {
        const int brow = row0 + grt;
        fc2_post(h2_prev + (size_t)brow * HH, W_fc2, b_fc2, out, brow, t - 1, tid, sY, sRed);
    }
}

// k2: attention for one batch row per WG.
__global__ __launch_bounds__(256) void k2(
    const float* __restrict__ c_seq,
    const float* __restrict__ W_abk, const float* __restrict__ b_abk,
    const float* __restrict__ h1_cur,
    const float* __restrict__ kap_old, float* __restrict__ kap_new,
    float* __restrict__ w_new)
{
    __shared__ float sH1[HH];
    __shared__ float sAbk[32];
    __shared__ float sAl[KWD], sBe[KWD], sKa[KWD];
    __shared__ float sPhi[UU];

    const int tid = threadIdx.x;
    const int b   = blockIdx.x;

    if (tid < HH / 4)
        ((float4*)sH1)[tid] = ((const float4*)(h1_cur + (size_t)b * HH))[tid];
    __syncthreads();

    {
        const int o = tid >> 3, kk = tid & 7;
        float acc = 0.f;
        if (o < 3 * KWD) {
            const float4* wp = (const float4*)(W_abk + (size_t)o * HH) + kk * 16;
            const float4* hp = (const float4*)sH1 + kk * 16;
#pragma unroll
            for (int k = 0; k < 16; ++k)
                acc += dot4(wp[k], hp[k]);
        }
        acc += __shfl_xor(acc, 1);
        acc += __shfl_xor(acc, 2);
        acc += __shfl_xor(acc, 4);
        if (o < 3 * KWD && kk == 0) sAbk[o] = acc + b_abk[o];
    }
    __syncthreads();

    if (tid < KWD) {
        const float al = expf(sAbk[tid]);
        const float be = expf(sAbk[KWD + tid]);
        const float ka = kap_old[(size_t)b * KWD + tid] + expf(sAbk[2 * KWD + tid]);
        sAl[tid] = al; sBe[tid] = be; sKa[tid] = ka;
        kap_new[(size_t)b * KWD + tid] = ka;
    }
    __syncthreads();

    if (tid < UU) {
        const float u = (float)tid;
        float s = 0.f;
#pragma unroll
        for (int k = 0; k < KWD; ++k) {
            const float d = sKa[k] - u;
            s += sAl[k] * expf(-sBe[k] * d * d);
        }
        sPhi[tid] = s;
    }
    __syncthreads();

    if (tid < AA) {
        float s = 0.f;
        const float* cp = c_seq + (size_t)b * UU * AA + tid;
#pragma unroll 4
        for (int u = 0; u < UU; ++u) s += sPhi[u] * cp[(size_t)u * AA];
        w_new[(size_t)b * AA + tid] = s;
    }
}

// k3: z2 = Wih2@[x,w,h1] + Whh2@h2_old + b; cell -> h2_new, c2.
__global__ __launch_bounds__(512, 4) void k3(
    const float* __restrict__ x,
    const float* __restrict__ Wih2, const float* __restrict__ Whh2,
    const float* __restrict__ bih2, const float* __restrict__ bhh2,
    const float* __restrict__ h1_cur, const float* __restrict__ w_cur,
    const float* __restrict__ h2_old, float* __restrict__ h2_new,
    float* __restrict__ c2, int t)
{
    __shared__ float sCat[MT][PC3];    // [x(3)|w(77)|h1(512)|h2(512)] = 276 f4
    __shared__ float sZp[4][MT][68];

    const int tid  = threadIdx.x;
    const int grt  = blockIdx.x;       // 0..31
    const int mtl  = blockIdx.y;       // 0..15
    const int row0 = mtl * MT, unit0 = grt * NJ;

    // ---- stage: 8 rows x 276 f4 ----
    {
        const int r = tid >> 6, c = tid & 63;
        const int b = row0 + r;
        const float4* s1 = (const float4*)(h1_cur + (size_t)b * HH);
        const float4* s2 = (const float4*)(h2_old + (size_t)b * HH);
        float4* d1 = (float4*)&sCat[r][IN1];          // cols 80..591
        float4* d2 = (float4*)&sCat[r][IN2];          // cols 592..1103
        for (int i = c; i < HH / 4; i += 64) { d1[i] = s1[i]; d2[i] = s2[i]; }
        for (int i = c; i < IN1; i += 64)
            sCat[r][i] = (i < INX) ? x[((size_t)b * TT + t) * INX + i]
                                   : w_cur[(size_t)b * AA + (i - INX)];
    }
    __syncthreads();

    // ---- GEMM: 4 gates per thread over K-quarter (276 f4 = 4 x 69) ----
    {
        const int m = tid & 7, j = (tid >> 3) & 15, kq = tid >> 7;
        const int i0 = kq * 69, i1 = i0 + 69;
        const int u = unit0 + j;
        float a0 = 0.f, a1 = 0.f, a2 = 0.f, a3 = 0.f;
        const float4* sc = (const float4*)&sCat[m][0];

        const float4* w0a = (const float4*)Wih2 + (size_t)u * 148;
        const float4* w1a = (const float4*)Wih2 + (size_t)(HH + u) * 148;
        const float4* w2a = (const float4*)Wih2 + (size_t)(2 * HH + u) * 148;
        const float4* w3a = (const float4*)Wih2 + (size_t)(3 * HH + u) * 148;
        const int aEnd = (i1 < 148) ? i1 : 148;
#pragma unroll 4
        for (int i = i0; i < aEnd; ++i) {
            float4 a = sc[i];
            a0 += dot4(w0a[i], a); a1 += dot4(w1a[i], a);
            a2 += dot4(w2a[i], a); a3 += dot4(w3a[i], a);
        }
        const float4* w0b = (const float4*)Whh2 + (size_t)u * 128;
        const float4* w1b = (const float4*)Whh2 + (size_t)(HH + u) * 128;
        const float4* w2b = (const float4*)Whh2 + (size_t)(2 * HH + u) * 128;
        const float4* w3b = (const float4*)Whh2 + (size_t)(3 * HH + u) * 128;
        const int bSt = (i0 > 148) ? i0 : 148;
#pragma unroll 4
        for (int i = bSt; i < i1; ++i) {
            float4 a = sc[i];
            const int k = i - 148;
            a0 += dot4(w0b[k], a); a1 += dot4(w1b[k], a);
            a2 += dot4(w2b[k], a); a3 += dot4(w3b[k], a);
        }
        sZp[kq][m][j]      = a0;
        sZp[kq][m][16 + j] = a1;
        sZp[kq][m][32 + j] = a2;
        sZp[kq][m][48 + j] = a3;
    }
    __syncthreads();

    // ---- cell ----
    if (tid < MT * NJ) {
        const int m = tid >> 4, j = tid & 15;
        const int u = unit0 + j;
        float z[4];
#pragma unroll
        for (int g = 0; g < 4; ++g) {
            const int wr = g * HH + u;
            z[g] = bih2[wr] + bhh2[wr]
                 + sZp[0][m][g * 16 + j] + sZp[1][m][g * 16 + j]
                 + sZp[2][m][g * 16 + j] + sZp[3][m][g * 16 + j];
        }
        const size_t gi = (size_t)(row0 + m) * HH + u;
        const float cold = c2[gi];
        const float cn = sigf(z[1]) * cold + sigf(z[0]) * tanhf(z[2]);
        c2[gi] = cn;
        h2_new[gi] = sigf(z[3]) * tanhf(cn);
    }
}

// Final fc2 for t = T-1.
__global__ __launch_bounds__(128) void fc2_final(
    const float* __restrict__ h2_last,
    const float* __restrict__ W_fc2, const float* __restrict__ b_fc2,
    float* __restrict__ out)
{
    __shared__ float sY[OUTD];
    __shared__ float sRed[2];
    const int brow = blockIdx.x;
    fc2_post(h2_last + (size_t)brow * HH, W_fc2, b_fc2, out, brow, TT - 1, threadIdx.x, sY, sRed);
}

extern "C" void kernel_launch(void* const* d_in, const int* in_sizes, int n_in,
                              void* d_out, int out_size, void* d_ws, size_t ws_size,
                              hipStream_t stream) {
    const float* x     = (const float*)d_in[0];
    const float* c_seq = (const float*)d_in[1];
    const float* Wih1  = (const float*)d_in[2];
    const float* Whh1  = (const float*)d_in[3];
    const float* bih1  = (const float*)d_in[4];
    const float* bhh1  = (const float*)d_in[5];
    const float* Wih2  = (const float*)d_in[6];
    const float* Whh2  = (const float*)d_in[7];
    const float* bih2  = (const float*)d_in[8];
    const float* bhh2  = (const float*)d_in[9];
    const float* W_abk = (const float*)d_in[10];
    const float* b_abk = (const float*)d_in[11];
    const float* W_fc2 = (const float*)d_in[12];
    const float* b_fc2 = (const float*)d_in[13];
    float* out = (float*)d_out;

    float* ws  = (float*)d_ws;
    float* h1b = ws;                     // 2*BH (double buffer)
    float* h2b = ws + 2 * BH;            // 2*BH
    float* c1  = ws + 4 * BH;            // BH
    float* c2  = ws + 5 * BH;            // BH
    float* kap = ws + 6 * BH;            // 2*BKW
    float* wb  = ws + 6 * BH + 2 * BKW;  // 2*BA
    const size_t used = (size_t)6 * BH + 2 * BKW + 2 * BA;

    hipMemsetAsync(d_ws, 0, used * sizeof(float), stream);

    const dim3 grid(GRT, MTL), blk(512);
    for (int t = 0; t < TT; ++t) {
        const int p = t & 1;
        k1<<<grid, blk, 0, stream>>>(x, Wih1, Whh1, bih1, bhh1, W_fc2, b_fc2,
                                     h1b + (size_t)p * BH, h1b + (size_t)(1 - p) * BH, c1,
                                     wb + (size_t)p * BA, h2b + (size_t)p * BH, out, t);
        k2<<<dim3(BB), dim3(256), 0, stream>>>(c_seq, W_abk, b_abk,
                                               h1b + (size_t)(1 - p) * BH,
                                               kap + (size_t)p * BKW, kap + (size_t)(1 - p) * BKW,
                                               wb + (size_t)(1 - p) * BA);
        k3<<<grid, blk, 0, stream>>>(x, Wih2, Whh2, bih2, bhh2,
                                     h1b + (size_t)(1 - p) * BH, wb + (size_t)(1 - p) * BA,
                                     h2b + (size_t)p * BH, h2b + (size_t)(1 - p) * BH, c2, t);
    }
    fc2_final<<<dim3(BB), dim3(128), 0, stream>>>(h2b, W_fc2, b_fc2, out);
}